// Round 9
// baseline (1094.573 us; speedup 1.0000x reference)
//
#include <hip/hip_runtime.h>
#include <hip/hip_fp16.h>

#define N_NODES 100000
#define N_EDGES 1600000
#define N_REL 4

// ---------------------------------------------------------------------------
// fp32 -> fp16 table conversion (x4 vectorized)
// ---------------------------------------------------------------------------
__global__ __launch_bounds__(256) void cvt_kernel(const float* __restrict__ in,
                                                  __half* __restrict__ out,
                                                  int n4) {
  int i = blockIdx.x * 256 + threadIdx.x;
  if (i >= n4) return;
  float4 v = ((const float4*)in)[i];
  __half2* o = (__half2*)(out + (long)i * 4);
  o[0] = __floats2half2_rn(v.x, v.y);
  o[1] = __floats2half2_rn(v.z, v.w);
}

// ---------------------------------------------------------------------------
// CSR build with deterministic, globally monotone offsets:
//   count -> blocksum -> scan(blocksums) -> alloc -> fill
// ---------------------------------------------------------------------------
__global__ __launch_bounds__(256) void count_kernel(const int* __restrict__ dst,
                                                    const int* __restrict__ et,
                                                    int* __restrict__ cnt,
                                                    int E, int N) {
  int e = blockIdx.x * 256 + threadIdx.x;
  if (e >= E) return;
  atomicAdd(&cnt[et[e] * N + dst[e]], 1);
}

__global__ __launch_bounds__(256) void blocksum_kernel(
    const int* __restrict__ cnt, int* __restrict__ bsum, int RN) {
  __shared__ int s[256];
  int i = blockIdx.x * 256 + threadIdx.x;
  s[threadIdx.x] = (i < RN) ? cnt[i] : 0;
  __syncthreads();
  for (int d = 128; d > 0; d >>= 1) {
    if (threadIdx.x < d) s[threadIdx.x] += s[threadIdx.x + d];
    __syncthreads();
  }
  if (threadIdx.x == 0) bsum[blockIdx.x] = s[0];
}

__global__ __launch_bounds__(256) void scanb_kernel(const int* __restrict__ bsum,
                                                    int* __restrict__ bbase,
                                                    int nB) {
  __shared__ int s[256];
  __shared__ int carry;
  if (threadIdx.x == 0) carry = 0;
  __syncthreads();
  for (int base = 0; base < nB; base += 256) {
    int i = base + threadIdx.x;
    int v = (i < nB) ? bsum[i] : 0;
    s[threadIdx.x] = v;
    __syncthreads();
    for (int d = 1; d < 256; d <<= 1) {
      int t = (threadIdx.x >= d) ? s[threadIdx.x - d] : 0;
      __syncthreads();
      s[threadIdx.x] += t;
      __syncthreads();
    }
    if (i < nB) bbase[i] = carry + s[threadIdx.x] - v;  // exclusive
    __syncthreads();
    if (threadIdx.x == 255) carry += s[255];
    __syncthreads();
  }
}

__global__ __launch_bounds__(256) void alloc_kernel(
    const int* __restrict__ cnt, const int* __restrict__ bbase,
    int* __restrict__ off, int* __restrict__ cur, int RN, int E) {
  __shared__ int s[256];
  int i = blockIdx.x * 256 + threadIdx.x;
  int c = (i < RN) ? cnt[i] : 0;
  s[threadIdx.x] = c;
  __syncthreads();
  for (int d = 1; d < 256; d <<= 1) {
    int t = (threadIdx.x >= d) ? s[threadIdx.x - d] : 0;
    __syncthreads();
    s[threadIdx.x] += t;
    __syncthreads();
  }
  if (i < RN) {
    int ex = bbase[blockIdx.x] + s[threadIdx.x] - c;
    off[i] = ex;
    cur[i] = ex;
  }
  if (i == 0) off[RN] = E;  // sentinel
}

__global__ __launch_bounds__(256) void fill_kernel(
    const int* __restrict__ src, const int* __restrict__ dst,
    const int* __restrict__ et, int* __restrict__ cur, int* __restrict__ eidx,
    int* __restrict__ ndst, int E, int N) {
  int e = blockIdx.x * 256 + threadIdx.x;
  if (e >= E) return;
  int d = dst[e];
  int seg = et[e] * N + d;
  int pos = atomicAdd(&cur[seg], 1);
  eidx[pos] = src[e];
  ndst[pos] = d;
}

// ---------------------------------------------------------------------------
// Fused layer kernel. Identical to R8 EXCEPT sAgg is flattened with a
// PADDED node stride S = N_REL*DIN + 1 (65 / 129 words, both == 1 mod 32):
// lanes with distinct local-node nl now hit distinct LDS banks, so the
// edge-sweep atomics serialize only on genuine same-address runs (~4-way),
// not 64-way same-bank (R8's 435 us failure).
// ---------------------------------------------------------------------------
template <int DIN, int DOUT, bool RELU, bool OUT_HALF>
__global__ __launch_bounds__(256, 8) void rgcn_layer_kernel(
    const __half* __restrict__ tab, const int* __restrict__ cnt,
    const int* __restrict__ off, const int* __restrict__ eidx,
    const int* __restrict__ ndst, const float* __restrict__ W,
    const float* __restrict__ root, const float* __restrict__ bias,
    void* __restrict__ outp, int N) {
  constexpr int GRAN = DIN / 8;        // 16B fp16 granules per row (2 or 4)
  constexpr int NB = 32;               // nodes per block (100000 = 3125*32)
  constexpr int S = N_REL * DIN + 1;   // padded node stride (odd mod 32)
  __shared__ float sAgg[NB * S];
  __shared__ float sX[NB][DIN];
  const int tid = threadIdx.x;
  const int n0 = blockIdx.x * NB;

  // zero accumulators
  for (int i = tid; i < NB * S; i += 256) sAgg[i] = 0.f;
  // stage self rows
  if (tid < NB * GRAN) {
    int nl = tid / GRAN, g = tid % GRAN;
    int node = n0 + nl;
    if (node < N) {
      union { float4 f; __half2 h[4]; } u;
      u.f = ((const float4*)tab)[(long)node * GRAN + g];
      float* d = &sX[nl][g * 8];
#pragma unroll
      for (int k = 0; k < 4; k++) {
        float2 f2 = __half22float2(u.h[k]);
        d[2 * k] = f2.x;
        d[2 * k + 1] = f2.y;
      }
    }
  }
  __syncthreads();

  // ---- flat edge sweeps ----
  const int wid = tid >> 6, lane = tid & 63;
  const int gg = wid % GRAN;        // granule this wave handles
  const int chunk = wid / GRAN;     // position-chunk this wave handles
  constexpr int CHUNKS = 4 / GRAN;  // 2 (DIN16) or 1 (DIN32)
#pragma unroll
  for (int r = 0; r < N_REL; r++) {
    int nend = n0 + NB;
    if (nend > N) nend = N;
    const int pStart = off[r * N + n0];
    const int pEnd = off[r * N + nend];  // monotone; off[RN]=E sentinel
    for (int p0 = pStart + chunk * 64; p0 < pEnd; p0 += CHUNKS * 64) {
      const int p = p0 + lane;
      if (p < pEnd) {
        const int sidx = eidx[p];
        const int nl = ndst[p] - n0;
        union { float4 f; __half2 h[4]; } u;
        u.f = ((const float4*)tab)[(long)sidx * GRAN + gg];
        float* d = &sAgg[nl * S + r * DIN + gg * 8];
#pragma unroll
        for (int k = 0; k < 4; k++) {
          float2 f2 = __half22float2(u.h[k]);
          atomicAdd(&d[2 * k], f2.x);
          atomicAdd(&d[2 * k + 1], f2.y);
        }
      }
    }
  }
  __syncthreads();

  // ---- divide by counts ----
  if (tid < NB * N_REL) {
    const int nl = tid >> 2, r = tid & 3;
    const int node = n0 + nl;
    if (node < N) {
      const int c = cnt[r * N + node];
      const float ic = (c > 0) ? 1.f / (float)c : 0.f;
#pragma unroll
      for (int ch = 0; ch < DIN; ch++) sAgg[nl * S + r * DIN + ch] *= ic;
    }
  }
  __syncthreads();

  // ---- dense transform ----
  constexpr int NPP = 256 / DOUT;
  constexpr int PASSES = NB / NPP;
  const int oc = tid % DOUT;
  const int nj0 = tid / DOUT;
#pragma unroll
  for (int p = 0; p < PASSES; p++) {
    const int nj = nj0 + p * NPP;
    const int node2 = n0 + nj;
    if (node2 < N) {
      float acc = bias[oc];
#pragma unroll
      for (int k = 0; k < DIN; k++) acc += sX[nj][k] * root[k * DOUT + oc];
#pragma unroll
      for (int r = 0; r < N_REL; r++) {
#pragma unroll
        for (int k = 0; k < DIN; k++)
          acc += sAgg[nj * S + r * DIN + k] * W[(r * DIN + k) * DOUT + oc];
      }
      if (RELU) acc = fmaxf(acc, 0.f);
      if (OUT_HALF)
        ((__half*)outp)[(long)node2 * DOUT + oc] = __float2half(acc);
      else
        ((float*)outp)[(long)node2 * DOUT + oc] = acc;
    }
  }
}

// ---------------------------------------------------------------------------
// Host launch
// ---------------------------------------------------------------------------
static inline size_t align256(size_t v) { return (v + 255) & ~(size_t)255; }

extern "C" void kernel_launch(void* const* d_in, const int* in_sizes, int n_in,
                              void* d_out, int out_size, void* d_ws,
                              size_t ws_size, hipStream_t stream) {
  const int N = N_NODES;
  const int E = N_EDGES;
  const int RN = N_REL * N;
  const int nB = (RN + 255) / 256;  // 1563 scan blocks

  const float* x = (const float*)d_in[0];
  const int* edge_index = (const int*)d_in[1];
  const int* et = (const int*)d_in[2];
  const float* W1 = (const float*)d_in[3];
  const float* root1 = (const float*)d_in[4];
  const float* b1 = (const float*)d_in[5];
  const float* W2 = (const float*)d_in[6];
  const float* root2 = (const float*)d_in[7];
  const float* b2 = (const float*)d_in[8];
  const float* W3 = (const float*)d_in[9];
  const float* root3 = (const float*)d_in[10];
  const float* b3 = (const float*)d_in[11];

  const int* src = edge_index;      // edge_index[0]
  const int* dst = edge_index + E;  // edge_index[1]

  // Workspace carve-up (~29 MB)
  char* ws = (char*)d_ws;
  size_t o = 0;
  int* cnt = (int*)(ws + o);
  o = align256(o + (size_t)RN * 4);
  int* off = (int*)(ws + o);
  o = align256(o + (size_t)(RN + 1) * 4);
  int* cur = (int*)(ws + o);
  o = align256(o + (size_t)RN * 4);
  int* bsum = (int*)(ws + o);
  o = align256(o + (size_t)nB * 4);
  int* bbase = (int*)(ws + o);
  o = align256(o + (size_t)nB * 4);
  int* eidx = (int*)(ws + o);
  o = align256(o + (size_t)E * 4);
  int* ndst = (int*)(ws + o);
  o = align256(o + (size_t)E * 4);
  __half* xh = (__half*)(ws + o);
  o = align256(o + (size_t)N * 16 * 2);
  __half* h1 = (__half*)(ws + o);
  o = align256(o + (size_t)N * 16 * 2);
  __half* h2 = (__half*)(ws + o);
  o = align256(o + (size_t)N * 32 * 2);
  (void)ws_size;

  float* out = (float*)d_out;

  const int gridE = (E + 255) / 256;
  const int gridL = N / 32;  // 3125, exact

  // --- CSR build (deterministic monotone offsets) + fp16 x ---
  hipMemsetAsync(cnt, 0, (size_t)RN * 4, stream);
  cvt_kernel<<<(N * 16 / 4 + 255) / 256, 256, 0, stream>>>(x, xh, N * 16 / 4);
  count_kernel<<<gridE, 256, 0, stream>>>(dst, et, cnt, E, N);
  blocksum_kernel<<<nB, 256, 0, stream>>>(cnt, bsum, RN);
  scanb_kernel<<<1, 256, 0, stream>>>(bsum, bbase, nB);
  alloc_kernel<<<nB, 256, 0, stream>>>(cnt, bbase, off, cur, RN, E);
  fill_kernel<<<gridE, 256, 0, stream>>>(src, dst, et, cur, eidx, ndst, E, N);

  // --- layer 1: 16 -> 16, relu, fp16 out ---
  rgcn_layer_kernel<16, 16, true, true><<<gridL, 256, 0, stream>>>(
      xh, cnt, off, eidx, ndst, W1, root1, b1, h1, N);
  // --- layer 2: 16 -> 32, relu, fp16 out ---
  rgcn_layer_kernel<16, 32, true, true><<<gridL, 256, 0, stream>>>(
      h1, cnt, off, eidx, ndst, W2, root2, b2, h2, N);
  // --- layer 3: 32 -> 64, no relu, fp32 out ---
  rgcn_layer_kernel<32, 64, false, false><<<gridL, 256, 0, stream>>>(
      h2, cnt, off, eidx, ndst, W3, root3, b3, out, N);
}

// Round 11
// 776.473 us; speedup vs baseline: 1.4097x; 1.4097x over previous
//
#include <hip/hip_runtime.h>
#include <hip/hip_fp16.h>

#define N_NODES 100000
#define N_EDGES 1600000
#define N_REL 4

// ---------------------------------------------------------------------------
// fp32 -> fp16 table conversion (x4 vectorized)
// ---------------------------------------------------------------------------
__global__ __launch_bounds__(256) void cvt_kernel(const float* __restrict__ in,
                                                  __half* __restrict__ out,
                                                  int n4) {
  int i = blockIdx.x * 256 + threadIdx.x;
  if (i >= n4) return;
  float4 v = ((const float4*)in)[i];
  __half2* o = (__half2*)(out + (long)i * 4);
  o[0] = __floats2half2_rn(v.x, v.y);
  o[1] = __floats2half2_rn(v.z, v.w);
}

// ---------------------------------------------------------------------------
// CSR build (deterministic, globally monotone offsets):
//   count -> blocksum -> scan(blocksums) -> alloc -> fill(nseg)
// ---------------------------------------------------------------------------
__global__ __launch_bounds__(256) void count_kernel(const int* __restrict__ dst,
                                                    const int* __restrict__ et,
                                                    int* __restrict__ cnt,
                                                    int E, int N) {
  int e = blockIdx.x * 256 + threadIdx.x;
  if (e >= E) return;
  atomicAdd(&cnt[et[e] * N + dst[e]], 1);
}

__global__ __launch_bounds__(256) void inv_kernel(const int* __restrict__ cnt,
                                                  float* __restrict__ inv,
                                                  int RN) {
  int i = blockIdx.x * 256 + threadIdx.x;
  if (i >= RN) return;
  int c = cnt[i];
  inv[i] = 1.0f / (float)(c > 1 ? c : 1);
}

__global__ __launch_bounds__(256) void blocksum_kernel(
    const int* __restrict__ cnt, int* __restrict__ bsum, int RN) {
  __shared__ int s[256];
  int i = blockIdx.x * 256 + threadIdx.x;
  s[threadIdx.x] = (i < RN) ? cnt[i] : 0;
  __syncthreads();
  for (int d = 128; d > 0; d >>= 1) {
    if (threadIdx.x < d) s[threadIdx.x] += s[threadIdx.x + d];
    __syncthreads();
  }
  if (threadIdx.x == 0) bsum[blockIdx.x] = s[0];
}

__global__ __launch_bounds__(256) void scanb_kernel(const int* __restrict__ bsum,
                                                    int* __restrict__ bbase,
                                                    int nB) {
  __shared__ int s[256];
  __shared__ int carry;
  if (threadIdx.x == 0) carry = 0;
  __syncthreads();
  for (int base = 0; base < nB; base += 256) {
    int i = base + threadIdx.x;
    int v = (i < nB) ? bsum[i] : 0;
    s[threadIdx.x] = v;
    __syncthreads();
    for (int d = 1; d < 256; d <<= 1) {
      int t = (threadIdx.x >= d) ? s[threadIdx.x - d] : 0;
      __syncthreads();
      s[threadIdx.x] += t;
      __syncthreads();
    }
    if (i < nB) bbase[i] = carry + s[threadIdx.x] - v;  // exclusive
    __syncthreads();
    if (threadIdx.x == 255) carry += s[255];
    __syncthreads();
  }
}

__global__ __launch_bounds__(256) void alloc_kernel(
    const int* __restrict__ cnt, const int* __restrict__ bbase,
    int* __restrict__ off, int* __restrict__ cur, int RN, int E) {
  __shared__ int s[256];
  int i = blockIdx.x * 256 + threadIdx.x;
  int c = (i < RN) ? cnt[i] : 0;
  s[threadIdx.x] = c;
  __syncthreads();
  for (int d = 1; d < 256; d <<= 1) {
    int t = (threadIdx.x >= d) ? s[threadIdx.x - d] : 0;
    __syncthreads();
    s[threadIdx.x] += t;
    __syncthreads();
  }
  if (i < RN) {
    int ex = bbase[blockIdx.x] + s[threadIdx.x] - c;
    off[i] = ex;
    cur[i] = ex;
  }
  if (i == 0) off[RN] = E;  // sentinel
}

__global__ __launch_bounds__(256) void fill_kernel(
    const int* __restrict__ src, const int* __restrict__ dst,
    const int* __restrict__ et, int* __restrict__ cur, int* __restrict__ eidx,
    int* __restrict__ nseg, int E, int N) {
  int e = blockIdx.x * 256 + threadIdx.x;
  if (e >= E) return;
  int seg = et[e] * N + dst[e];
  int pos = atomicAdd(&cur[seg], 1);
  eidx[pos] = src[e];
  nseg[pos] = seg;
}

// ---------------------------------------------------------------------------
// Segmented reduce over sorted CSR positions — NO loops, NO LDS atomics.
// Wave window = WEDGE=64/GRAN consecutive edges; lane=(edge j, granule g).
// Gather one 16B fp16 granule (full rows covered per wave -> full-line use),
// wave segmented inclusive scan by key (shfl width WEDGE), run-tail lanes
// write run-sums to sums[seg]: plain float4 stores if the segment is fully
// inside the window (checked via off[]), global atomicAdd (rare) if it spans.
// ---------------------------------------------------------------------------
template <int GRAN>
__global__ __launch_bounds__(256) void seg_reduce_kernel(
    const __half* __restrict__ tab, const int* __restrict__ eidx,
    const int* __restrict__ nseg, const int* __restrict__ off,
    float* __restrict__ sums, int E) {
  constexpr int WEDGE = 64 / GRAN;  // edges per wave window
  constexpr int DIN = GRAN * 8;
  const int lane = threadIdx.x & 63;
  const int wv = threadIdx.x >> 6;  // 4 waves per block
  const int j = lane % WEDGE;
  const int g = lane / WEDGE;
  const int pw = (blockIdx.x * 4 + wv) * WEDGE;  // window start position
  const int p = pw + j;
  if (p >= E) return;  // uniform per wave (E % WEDGE == 0)

  const int sidx = eidx[p];
  const int key = nseg[p];
  union { float4 f; __half2 h[4]; } u;
  u.f = ((const float4*)tab)[(long)sidx * GRAN + g];
  float v[8];
#pragma unroll
  for (int k = 0; k < 4; k++) {
    float2 f2 = __half22float2(u.h[k]);
    v[2 * k] = f2.x;
    v[2 * k + 1] = f2.y;
  }

  // segmented inclusive scan (keys sorted within window)
#pragma unroll
  for (int d = 1; d < WEDGE; d <<= 1) {
    const int okey = __shfl_up(key, d, WEDGE);
    const bool take = (j >= d) && (okey == key);
#pragma unroll
    for (int k = 0; k < 8; k++) {
      const float ov = __shfl_up(v[k], d, WEDGE);
      v[k] += take ? ov : 0.f;
    }
  }

  const int nkey = __shfl_down(key, 1, WEDGE);
  if (j == WEDGE - 1 || nkey != key) {  // run tail
    const int segStart = off[key];
    const int segEnd = off[key + 1];
    float* dp = sums + (long)key * DIN + g * 8;
    if (segStart < pw || segEnd > pw + WEDGE) {  // spans window boundary
#pragma unroll
      for (int k = 0; k < 8; k++) atomicAdd(dp + k, v[k]);
    } else {  // exclusive ownership
      ((float4*)dp)[0] = make_float4(v[0], v[1], v[2], v[3]);
      ((float4*)dp)[1] = make_float4(v[4], v[5], v[6], v[7]);
    }
  }
}

// ---------------------------------------------------------------------------
// Streaming transform: out = bias + self@root + sum_r (inv_r * sums_r) @ W_r.
// Block = 32 nodes. Stage inv + self + scaled sums in LDS (all coalesced),
// then thread=(node,oc) dense mini-matmul; W/root broadcast-read from L1.
// ---------------------------------------------------------------------------
template <int DIN, int DOUT, bool RELU, bool OUT_HALF>
__global__ __launch_bounds__(256, 4) void transform_kernel(
    const __half* __restrict__ tab, const float* __restrict__ sums,
    const float* __restrict__ inv, const float* __restrict__ W,
    const float* __restrict__ root, const float* __restrict__ bias,
    void* __restrict__ outp, int N) {
  constexpr int NB = 32;
  constexpr int GRAN = DIN / 8;
  __shared__ float sAgg[NB][N_REL][DIN];
  __shared__ float sX[NB][DIN];
  __shared__ float sInv[NB * N_REL];
  const int tid = threadIdx.x;
  const int n0 = blockIdx.x * NB;  // N % 32 == 0, no bounds checks needed

  if (tid < NB * N_REL) {  // coalesced inv stage: r = tid>>5, nl = tid&31
    const int r = tid >> 5, nl = tid & 31;
    sInv[nl * N_REL + r] = inv[r * N + n0 + nl];
  }
  if (tid < NB * GRAN) {  // self rows (fp16 -> fp32)
    const int nl = tid / GRAN, g = tid % GRAN;
    union { float4 f; __half2 h[4]; } u;
    u.f = ((const float4*)tab)[(long)(n0 + nl) * GRAN + g];
    float* d = &sX[nl][g * 8];
#pragma unroll
    for (int k = 0; k < 4; k++) {
      float2 f2 = __half22float2(u.h[k]);
      d[2 * k] = f2.x;
      d[2 * k + 1] = f2.y;
    }
  }
  __syncthreads();

  // stage sums * inv (global reads fully coalesced per relation row-block)
#pragma unroll
  for (int r = 0; r < N_REL; r++) {
    for (int idx = tid; idx < NB * DIN; idx += 256) {
      const int nl = idx / DIN;
      (&sAgg[0][r][0])[(idx / DIN) * (N_REL * DIN) + (idx % DIN)] =
          sums[((long)r * N + n0) * DIN + idx] * sInv[nl * N_REL + r];
    }
  }
  __syncthreads();

  constexpr int NPP = 256 / DOUT;
  constexpr int PASSES = NB / NPP;
  const int oc = tid % DOUT;
  const int nj0 = tid / DOUT;
#pragma unroll
  for (int pss = 0; pss < PASSES; pss++) {
    const int nj = nj0 + pss * NPP;
    const int node2 = n0 + nj;
    float acc = bias[oc];
#pragma unroll
    for (int k = 0; k < DIN; k++) acc += sX[nj][k] * root[k * DOUT + oc];
#pragma unroll
    for (int r = 0; r < N_REL; r++) {
#pragma unroll
      for (int k = 0; k < DIN; k++)
        acc += sAgg[nj][r][k] * W[(r * DIN + k) * DOUT + oc];
    }
    if (RELU) acc = fmaxf(acc, 0.f);
    if (OUT_HALF)
      ((__half*)outp)[(long)node2 * DOUT + oc] = __float2half(acc);
    else
      ((float*)outp)[(long)node2 * DOUT + oc] = acc;
  }
}

// ---------------------------------------------------------------------------
// Host launch
// ---------------------------------------------------------------------------
static inline size_t align256(size_t v) { return (v + 255) & ~(size_t)255; }

extern "C" void kernel_launch(void* const* d_in, const int* in_sizes, int n_in,
                              void* d_out, int out_size, void* d_ws,
                              size_t ws_size, hipStream_t stream) {
  const int N = N_NODES;
  const int E = N_EDGES;
  const int RN = N_REL * N;
  const int nB = (RN + 255) / 256;

  const float* x = (const float*)d_in[0];
  const int* edge_index = (const int*)d_in[1];
  const int* et = (const int*)d_in[2];
  const float* W1 = (const float*)d_in[3];
  const float* root1 = (const float*)d_in[4];
  const float* b1 = (const float*)d_in[5];
  const float* W2 = (const float*)d_in[6];
  const float* root2 = (const float*)d_in[7];
  const float* b2 = (const float*)d_in[8];
  const float* W3 = (const float*)d_in[9];
  const float* root3 = (const float*)d_in[10];
  const float* b3 = (const float*)d_in[11];

  const int* src = edge_index;      // edge_index[0]
  const int* dst = edge_index + E;  // edge_index[1]

  // Workspace carve-up (~83 MB)
  char* ws = (char*)d_ws;
  size_t o = 0;
  int* cnt = (int*)(ws + o);
  o = align256(o + (size_t)RN * 4);
  int* off = (int*)(ws + o);
  o = align256(o + (size_t)(RN + 1) * 4);
  int* cur = (int*)(ws + o);
  o = align256(o + (size_t)RN * 4);
  int* bsum = (int*)(ws + o);
  o = align256(o + (size_t)nB * 4);
  int* bbase = (int*)(ws + o);
  o = align256(o + (size_t)nB * 4);
  int* eidx = (int*)(ws + o);
  o = align256(o + (size_t)E * 4);
  int* nseg = (int*)(ws + o);
  o = align256(o + (size_t)E * 4);
  float* inv = (float*)(ws + o);
  o = align256(o + (size_t)RN * 4);
  __half* xh = (__half*)(ws + o);
  o = align256(o + (size_t)N * 16 * 2);
  __half* h1 = (__half*)(ws + o);
  o = align256(o + (size_t)N * 16 * 2);
  __half* h2 = (__half*)(ws + o);
  o = align256(o + (size_t)N * 32 * 2);
  float* sums = (float*)(ws + o);
  o = align256(o + (size_t)RN * 32 * 4);  // 51.2 MB (max DIN=32)
  (void)ws_size;

  float* out = (float*)d_out;
  const int gridE = (E + 255) / 256;
  const int gridT = N / 32;  // 3125, exact

  // --- CSR build + inv + fp16 x ---
  hipMemsetAsync(cnt, 0, (size_t)RN * 4, stream);
  cvt_kernel<<<(N * 16 / 4 + 255) / 256, 256, 0, stream>>>(x, xh, N * 16 / 4);
  count_kernel<<<gridE, 256, 0, stream>>>(dst, et, cnt, E, N);
  inv_kernel<<<(RN + 255) / 256, 256, 0, stream>>>(cnt, inv, RN);
  blocksum_kernel<<<nB, 256, 0, stream>>>(cnt, bsum, RN);
  scanb_kernel<<<1, 256, 0, stream>>>(bsum, bbase, nB);
  alloc_kernel<<<nB, 256, 0, stream>>>(cnt, bbase, off, cur, RN, E);
  fill_kernel<<<gridE, 256, 0, stream>>>(src, dst, et, cur, eidx, nseg, E, N);

  // --- layer 1: 16 -> 16, relu, fp16 out ---
  hipMemsetAsync(sums, 0, (size_t)RN * 16 * 4, stream);
  seg_reduce_kernel<2><<<E / 128, 256, 0, stream>>>(xh, eidx, nseg, off, sums, E);
  transform_kernel<16, 16, true, true><<<gridT, 256, 0, stream>>>(
      xh, sums, inv, W1, root1, b1, h1, N);

  // --- layer 2: 16 -> 32, relu, fp16 out ---
  hipMemsetAsync(sums, 0, (size_t)RN * 16 * 4, stream);
  seg_reduce_kernel<2><<<E / 128, 256, 0, stream>>>(h1, eidx, nseg, off, sums, E);
  transform_kernel<16, 32, true, true><<<gridT, 256, 0, stream>>>(
      h1, sums, inv, W2, root2, b2, h2, N);

  // --- layer 3: 32 -> 64, no relu, fp32 out ---
  hipMemsetAsync(sums, 0, (size_t)RN * 32 * 4, stream);
  seg_reduce_kernel<4><<<E / 64, 256, 0, stream>>>(h2, eidx, nseg, off, sums, E);
  transform_kernel<32, 64, false, false><<<gridT, 256, 0, stream>>>(
      h2, sums, inv, W3, root3, b3, out, N);
}